// Round 14
// baseline (42.371 us; speedup 1.0000x reference)
//
#include <hip/hip_runtime.h>
#include <math.h>

#define B 8
#define S 4096
#define H 1024
#define NSEG 64
#define NPARA 32
#define NA 8
#define BS (B * S)
#define ROWS_PER_BLK 16
#define BLKS_PER_B (S / ROWS_PER_BLK)      // 256
#define NBLK (B * BLKS_PER_B)              // 2048

// online-LSE merge: x = running max (m), y = running scaled sum (s)
__device__ __forceinline__ float2 lse_merge(float2 A, float2 Bv)
{
    float m = fmaxf(A.x, Bv.x);
    float s = 0.f;
    if (A.y > 0.f)  s += A.y * expf(A.x - m);
    if (Bv.y > 0.f) s += Bv.y * expf(Bv.x - m);
    return make_float2(m, s);
}

// ---------------------------------------------------------------------------
// Kernel 1: R10 champion with ONE change — rows processed in PAIRS.
// 8 loads in flight per window (was 4) + two independent reduce chains (ILP).
// Block k: 16 contiguous rows of batch k/256, one wave per 4 rows.
// ---------------------------------------------------------------------------
__global__ __launch_bounds__(256) void dots_kernel(
    const float* __restrict__ seq,
    const float* __restrict__ Wqa,
    const float* __restrict__ Wsp,
    const float* __restrict__ Wrank,
    const int*   __restrict__ tt,
    float* __restrict__ scores,
    float4* __restrict__ lse_part,
    float* __restrict__ out)
{
    if (blockIdx.x == 0 && threadIdx.x == 0) {
        out[0] = 0.f; out[1] = 0.f; out[2] = 0.f;
    }
    const int blk   = blockIdx.x;
    const int b     = blk >> 8;                 // batch
    const int rbase = (blk & 255) * ROWS_PER_BLK;
    const int w     = threadIdx.x >> 6;
    const int lane  = threadIdx.x & 63;

    __shared__ float  blkres[4][ROWS_PER_BLK];
    __shared__ float4 lsep[4];

    // preload weights (lane handles float4 chunks lane + 64*c)
    float wq0[4][4], wq1[4][4];
    float4 wspv[4], wrkv[4];
#pragma unroll
    for (int c = 0; c < 4; ++c) {
        int h0 = (lane + 64 * c) * 4;
#pragma unroll
        for (int j = 0; j < 4; ++j) {
            wq0[c][j] = Wqa[(h0 + j) * 2 + 0];
            wq1[c][j] = Wqa[(h0 + j) * 2 + 1];
        }
        wspv[c] = *(const float4*)(Wsp + h0);
        wrkv[c] = *(const float4*)(Wrank + h0);
    }

    const int* ttb = tt + b * S;
    float m0 = -INFINITY, s0 = 0.f, m1 = -INFINITY, s1 = 0.f;

#pragma unroll
    for (int ip = 0; ip < 2; ++ip) {
        const int r0 = rbase + w * 4 + 2 * ip;      // first row of pair
        const float4* row0 = (const float4*)(seq + ((size_t)b * S + r0) * H);
        const float4* row1 = row0 + (H / 4);

        float a0 = 0.f, a1 = 0.f, a2 = 0.f, a3 = 0.f;   // row r0
        float c0 = 0.f, c1 = 0.f, c2 = 0.f, c3 = 0.f;   // row r0+1
#pragma unroll
        for (int c = 0; c < 4; ++c) {
            float4 u = row0[lane + 64 * c];
            float4 v = row1[lane + 64 * c];
            a0 += u.x * wq0[c][0] + u.y * wq0[c][1] + u.z * wq0[c][2] + u.w * wq0[c][3];
            c0 += v.x * wq0[c][0] + v.y * wq0[c][1] + v.z * wq0[c][2] + v.w * wq0[c][3];
            a1 += u.x * wq1[c][0] + u.y * wq1[c][1] + u.z * wq1[c][2] + u.w * wq1[c][3];
            c1 += v.x * wq1[c][0] + v.y * wq1[c][1] + v.z * wq1[c][2] + v.w * wq1[c][3];
            a2 += u.x * wspv[c].x + u.y * wspv[c].y + u.z * wspv[c].z + u.w * wspv[c].w;
            c2 += v.x * wspv[c].x + v.y * wspv[c].y + v.z * wspv[c].z + v.w * wspv[c].w;
            a3 += u.x * wrkv[c].x + u.y * wrkv[c].y + u.z * wrkv[c].z + u.w * wrkv[c].w;
            c3 += v.x * wrkv[c].x + v.y * wrkv[c].y + v.z * wrkv[c].z + v.w * wrkv[c].w;
        }
        // two independent butterflies, interleaved for ILP
#pragma unroll
        for (int off = 32; off > 0; off >>= 1) {
            a0 += __shfl_xor(a0, off);
            c0 += __shfl_xor(c0, off);
            a1 += __shfl_xor(a1, off);
            c1 += __shfl_xor(c1, off);
            a2 += __shfl_xor(a2, off);
            c2 += __shfl_xor(c2, off);
            a3 += __shfl_xor(a3, off);
            c3 += __shfl_xor(c3, off);
        }
        // fused online masked LSE for both rows (lane-uniform; biases cancel)
        if (ttb[r0] == 1) {
            float mn = fmaxf(m0, a0);
            s0 = s0 * expf(m0 - mn) + expf(a0 - mn); m0 = mn;
            mn = fmaxf(m1, a1);
            s1 = s1 * expf(m1 - mn) + expf(a1 - mn); m1 = mn;
        }
        if (ttb[r0 + 1] == 1) {
            float mn = fmaxf(m0, c0);
            s0 = s0 * expf(m0 - mn) + expf(c0 - mn); m0 = mn;
            mn = fmaxf(m1, c1);
            s1 = s1 * expf(m1 - mn) + expf(c1 - mn); m1 = mn;
        }
        if (lane == 0) {
            const int idx = w * 4 + 2 * ip;
            blkres[0][idx] = a0; blkres[1][idx] = a1;
            blkres[2][idx] = a2; blkres[3][idx] = a3;
            blkres[0][idx + 1] = c0; blkres[1][idx + 1] = c1;
            blkres[2][idx + 1] = c2; blkres[3][idx + 1] = c3;
        }
    }
    if (lane == 0) lsep[w] = make_float4(m0, s0, m1, s1);
    __syncthreads();

    const int t = threadIdx.x;
    if (t < 64) {   // coalesced score writes: 4 planes x 16 floats
        const int p = t >> 4, idx = t & 15;
        scores[p * BS + b * S + rbase + idx] = blkres[p][idx];
    }
    if (t == 0) {   // merge the 4 wave partials
        float2 L0 = make_float2(lsep[0].x, lsep[0].y);
        float2 L1 = make_float2(lsep[0].z, lsep[0].w);
#pragma unroll
        for (int i = 1; i < 4; ++i) {
            L0 = lse_merge(L0, make_float2(lsep[i].x, lsep[i].y));
            L1 = lse_merge(L1, make_float2(lsep[i].z, lsep[i].w));
        }
        lse_part[blk] = make_float4(L0.x, L0.y, L1.x, L1.y);
    }
}

// ---------------------------------------------------------------------------
// block reduce (sum) for ListMLE
// ---------------------------------------------------------------------------
__device__ __forceinline__ float blk_reduce1(float v, float* wred1, int t)
{
    const int lane = t & 63, w = t >> 6;
#pragma unroll
    for (int off = 32; off > 0; off >>= 1) v += __shfl_xor(v, off);
    if (lane == 0) wred1[w] = v;
    __syncthreads();
    float r = wred1[0] + wred1[1] + wred1[2] + wred1[3];
    __syncthreads();
    return r;
}

__device__ float listmle_block(const float* fs, const float* fl, float* se,
                               int n, float* wred1, int t)
{
    if (t < n) se[t] = (fl[t] != -1.0f) ? expf(fs[t]) : 0.0f;
    __syncthreads();
    float lp = 0.0f;
    if (t < n && fl[t] >= 0.5f) {
        float fj = fl[t];
        float rest = 0.0f;
        for (int k = 0; k < n; ++k)
            if (fl[k] < fj) rest += se[k];
        lp = fs[t] - logf(se[t] + rest);
    }
    float tot = blk_reduce1(lp, wred1, t);
    return -tot;
}

// ---------------------------------------------------------------------------
// Kernel 2 (R10 champion, verbatim): one block per batch. Merge LSE
// partials, DIRECT per-segment sums of p2 (4 threads/segment), 2x ListMLE,
// parallel span loss; atomicAdd into out.
// ---------------------------------------------------------------------------
__global__ __launch_bounds__(256) void batch_kernel(
    const float*  __restrict__ scores,
    const float4* __restrict__ lse_part,
    const int*    __restrict__ tt,
    const int*    __restrict__ sent_starts,
    const int*    __restrict__ para_starts,
    const float*  __restrict__ para_labels,
    const float*  __restrict__ sp_labels,
    const int*    __restrict__ starts,
    const int*    __restrict__ ends,
    float* __restrict__ out)
{
    const int b = blockIdx.x;
    const int t = threadIdx.x;
    const int lane = t & 63, w = t >> 6;

    __shared__ float4 lsew[4];
    __shared__ float  wred1[4];
    __shared__ float  fsb[1 + NSEG], flb[1 + NSEG], seb[1 + NSEG];
    __shared__ float  lse_sh[2];
    __shared__ int    ssh[NSEG + 1];

    const float* p0 = scores + 0 * BS + b * S;
    const float* p1 = scores + 1 * BS + b * S;
    const float* p2 = scores + 2 * BS + b * S;
    const float* p3 = scores + 3 * BS + b * S;
    const int*   ttb = tt + b * S;

    if (t < NSEG + 1) ssh[t] = sent_starts[b * (NSEG + 1) + t];

    // ---- merge 256 LSE partials ---------------------------------------------
    {
        float4 P = lse_part[b * BLKS_PER_B + t];
        float2 L0 = make_float2(P.x, P.y);
        float2 L1 = make_float2(P.z, P.w);
#pragma unroll
        for (int off = 32; off > 0; off >>= 1) {
            float2 O0 = make_float2(__shfl_xor(L0.x, off), __shfl_xor(L0.y, off));
            float2 O1 = make_float2(__shfl_xor(L1.x, off), __shfl_xor(L1.y, off));
            L0 = lse_merge(L0, O0);
            L1 = lse_merge(L1, O1);
        }
        if (lane == 0) lsew[w] = make_float4(L0.x, L0.y, L1.x, L1.y);
        __syncthreads();
        if (t == 0) {
            float2 M0 = make_float2(lsew[0].x, lsew[0].y);
            float2 M1 = make_float2(lsew[0].z, lsew[0].w);
#pragma unroll
            for (int i = 1; i < 4; ++i) {
                M0 = lse_merge(M0, make_float2(lsew[i].x, lsew[i].y));
                M1 = lse_merge(M1, make_float2(lsew[i].z, lsew[i].w));
            }
            lse_sh[0] = M0.x + logf(M0.y);
            lse_sh[1] = M1.x + logf(M1.y);
        }
    }

    // ---- direct per-segment sums of p2 (4 threads per segment) --------------
    {
        const int j  = t >> 2;        // segment 0..63
        const int l4 = t & 3;
        int st = ssh[j];
        int en = ssh[j + 1];
        if (en != -1) {
            int stc = min(max(st, 0), S);
            int enc = max(min(max(en, 0), S), stc + 1);
            float x = 0.f;
            for (int s = stc + l4; s < enc; s += 4) x += p2[s];
            x += __shfl_xor(x, 1);
            x += __shfl_xor(x, 2);
            if (l4 == 0) {
                fsb[1 + j] = x / (float)(enc - stc);
                flb[1 + j] = sp_labels[b * NSEG + j];
            }
        } else {
            if (l4 == 0) {
                fsb[1 + j] = p2[S - 1];       // d_sp at last row
                flb[1 + j] = sp_labels[b * NSEG + j];
            }
        }
        if (t == 0) { fsb[0] = p2[0]; flb[0] = 0.5f; }   // sent_thres
    }
    __syncthreads();
    float sp_loss_b = listmle_block(fsb, flb, seb, 1 + NSEG, wred1, t);

    // ---- rank ListMLE -------------------------------------------------------
    if (t == 0) { fsb[0] = p3[0]; flb[0] = 0.5f; }
    if (t < NPARA) {
        int ps = para_starts[b * NPARA + t];
        fsb[1 + t] = p3[ps];
        flb[1 + t] = para_labels[b * NPARA + t];
    }
    __syncthreads();
    float rank_loss_b = listmle_block(fsb, flb, seb, 1 + NPARA, wred1, t);

    // ---- span loss (parallel over answers) ----------------------------------
    float e_a = 0.f;
    if (t < NA) {
        const float lse0 = lse_sh[0], lse1 = lse_sh[1];
        int tsv = starts[b * NA + t];
        int tev = ends[b * NA + t];
        float lt = 0.f;
        if (tsv != -1) {
            int sf = min(max(tsv, 0), S - 1);
            float sl = (ttb[sf] == 1) ? p0[sf] : -INFINITY;
            lt += -(sl - lse0);
        }
        if (tev != -1) {
            int sf = min(max(tev, 0), S - 1);
            float el = (ttb[sf] == 1) ? p1[sf] : -INFINITY;
            lt += -(el - lse1);
        }
        float lp = -lt;
        e_a = (lp == 0.0f) ? 0.f : expf(lp);
    }
#pragma unroll
    for (int off = 4; off > 0; off >>= 1) e_a += __shfl_xor(e_a, off, 8);
    if (t == 0) {
        float logm = (e_a > 0.f) ? logf(e_a) : 0.f;
        atomicAdd(out + 0, rank_loss_b + sp_loss_b - logm);
        atomicAdd(out + 1, rank_loss_b);
        atomicAdd(out + 2, sp_loss_b);
    }
}

extern "C" void kernel_launch(void* const* d_in, const int* in_sizes, int n_in,
                              void* d_out, int out_size, void* d_ws, size_t ws_size,
                              hipStream_t stream)
{
    const float* seq         = (const float*)d_in[0];
    const int*   tt          = (const int*)  d_in[1];
    const int*   sent_starts = (const int*)  d_in[2];
    const int*   para_starts = (const int*)  d_in[3];
    const float* para_labels = (const float*)d_in[4];
    const float* sp_labels   = (const float*)d_in[5];
    const int*   starts      = (const int*)  d_in[6];
    const int*   ends        = (const int*)  d_in[7];
    const float* Wqa         = (const float*)d_in[8];
    const float* Wrank       = (const float*)d_in[10];
    const float* Wsp         = (const float*)d_in[12];

    float*  out      = (float*)d_out;
    float*  scores   = (float*)d_ws;                       // planar (4, B*S)
    float4* lse_part = (float4*)(scores + 4 * (size_t)BS); // NBLK float4

    dots_kernel<<<NBLK, 256, 0, stream>>>(seq, Wqa, Wsp, Wrank, tt,
                                          scores, lse_part, out);
    batch_kernel<<<B, 256, 0, stream>>>(scores, lse_part, tt, sent_starts,
                                        para_starts, para_labels, sp_labels,
                                        starts, ends, out);
}

// Round 15
// 38.470 us; speedup vs baseline: 1.1014x; 1.1014x over previous
//
#include <hip/hip_runtime.h>
#include <math.h>

#define B 8
#define S 4096
#define H 1024
#define NSEG 64
#define NPARA 32
#define NA 8
#define BS (B * S)
#define ROWS_PER_BLK 16
#define BLKS_PER_B (S / ROWS_PER_BLK)      // 256
#define NBLK (B * BLKS_PER_B)              // 2048

// online-LSE merge: x = running max (m), y = running scaled sum (s)
__device__ __forceinline__ float2 lse_merge(float2 A, float2 Bv)
{
    float m = fmaxf(A.x, Bv.x);
    float s = 0.f;
    if (A.y > 0.f)  s += A.y * expf(A.x - m);
    if (Bv.y > 0.f) s += Bv.y * expf(Bv.x - m);
    return make_float2(m, s);
}

// ---------------------------------------------------------------------------
// Kernel 1 (R10 champion, restored verbatim): per-row 4-way dots + fused
// online masked logsumexp partials. Block k handles 16 contiguous rows of
// batch k/256. One wave per 4 rows. Planar scores (4, B*S).
// ---------------------------------------------------------------------------
__global__ __launch_bounds__(256) void dots_kernel(
    const float* __restrict__ seq,
    const float* __restrict__ Wqa,
    const float* __restrict__ Wsp,
    const float* __restrict__ Wrank,
    const int*   __restrict__ tt,
    float* __restrict__ scores,
    float4* __restrict__ lse_part,
    float* __restrict__ out)
{
    if (blockIdx.x == 0 && threadIdx.x == 0) {
        out[0] = 0.f; out[1] = 0.f; out[2] = 0.f;
    }
    const int blk   = blockIdx.x;
    const int b     = blk >> 8;                 // batch
    const int rbase = (blk & 255) * ROWS_PER_BLK;
    const int w     = threadIdx.x >> 6;
    const int lane  = threadIdx.x & 63;

    __shared__ float  blkres[4][ROWS_PER_BLK];
    __shared__ float4 lsep[4];

    // preload weights (lane handles float4 chunks lane + 64*c)
    float wq0[4][4], wq1[4][4];
    float4 wspv[4], wrkv[4];
#pragma unroll
    for (int c = 0; c < 4; ++c) {
        int h0 = (lane + 64 * c) * 4;
#pragma unroll
        for (int j = 0; j < 4; ++j) {
            wq0[c][j] = Wqa[(h0 + j) * 2 + 0];
            wq1[c][j] = Wqa[(h0 + j) * 2 + 1];
        }
        wspv[c] = *(const float4*)(Wsp + h0);
        wrkv[c] = *(const float4*)(Wrank + h0);
    }

    const int* ttb = tt + b * S;
    float m0 = -INFINITY, s0 = 0.f, m1 = -INFINITY, s1 = 0.f;

    for (int i = 0; i < 4; ++i) {
        const int srow = rbase + w * 4 + i;
        const float4* row = (const float4*)(seq + ((size_t)b * S + srow) * H);
        float a0 = 0.f, a1 = 0.f, a2 = 0.f, a3 = 0.f;
#pragma unroll
        for (int c = 0; c < 4; ++c) {
            float4 v = row[lane + 64 * c];
            a0 += v.x * wq0[c][0] + v.y * wq0[c][1] + v.z * wq0[c][2] + v.w * wq0[c][3];
            a1 += v.x * wq1[c][0] + v.y * wq1[c][1] + v.z * wq1[c][2] + v.w * wq1[c][3];
            a2 += v.x * wspv[c].x + v.y * wspv[c].y + v.z * wspv[c].z + v.w * wspv[c].w;
            a3 += v.x * wrkv[c].x + v.y * wrkv[c].y + v.z * wrkv[c].z + v.w * wrkv[c].w;
        }
#pragma unroll
        for (int off = 32; off > 0; off >>= 1) {
            a0 += __shfl_xor(a0, off);
            a1 += __shfl_xor(a1, off);
            a2 += __shfl_xor(a2, off);
            a3 += __shfl_xor(a3, off);
        }
        // fused online masked LSE (lane-uniform, biases cancel: shift-invariant)
        if (ttb[srow] == 1) {
            float mn = fmaxf(m0, a0);
            s0 = s0 * expf(m0 - mn) + expf(a0 - mn); m0 = mn;
            mn = fmaxf(m1, a1);
            s1 = s1 * expf(m1 - mn) + expf(a1 - mn); m1 = mn;
        }
        if (lane == 0) {
            const int idx = w * 4 + i;
            blkres[0][idx] = a0; blkres[1][idx] = a1;
            blkres[2][idx] = a2; blkres[3][idx] = a3;
        }
    }
    if (lane == 0) lsep[w] = make_float4(m0, s0, m1, s1);
    __syncthreads();

    const int t = threadIdx.x;
    if (t < 64) {   // coalesced score writes: 4 planes x 16 floats
        const int p = t >> 4, idx = t & 15;
        scores[p * BS + b * S + rbase + idx] = blkres[p][idx];
    }
    if (t == 0) {   // merge the 4 wave partials
        float2 L0 = make_float2(lsep[0].x, lsep[0].y);
        float2 L1 = make_float2(lsep[0].z, lsep[0].w);
#pragma unroll
        for (int i = 1; i < 4; ++i) {
            L0 = lse_merge(L0, make_float2(lsep[i].x, lsep[i].y));
            L1 = lse_merge(L1, make_float2(lsep[i].z, lsep[i].w));
        }
        lse_part[blk] = make_float4(L0.x, L0.y, L1.x, L1.y);
    }
}

// ---------------------------------------------------------------------------
// block reduce (sum) for ListMLE
// ---------------------------------------------------------------------------
__device__ __forceinline__ float blk_reduce1(float v, float* wred1, int t)
{
    const int lane = t & 63, w = t >> 6;
#pragma unroll
    for (int off = 32; off > 0; off >>= 1) v += __shfl_xor(v, off);
    if (lane == 0) wred1[w] = v;
    __syncthreads();
    float r = wred1[0] + wred1[1] + wred1[2] + wred1[3];
    __syncthreads();
    return r;
}

__device__ float listmle_block(const float* fs, const float* fl, float* se,
                               int n, float* wred1, int t)
{
    if (t < n) se[t] = (fl[t] != -1.0f) ? expf(fs[t]) : 0.0f;
    __syncthreads();
    float lp = 0.0f;
    if (t < n && fl[t] >= 0.5f) {
        float fj = fl[t];
        float rest = 0.0f;
        for (int k = 0; k < n; ++k)
            if (fl[k] < fj) rest += se[k];
        lp = fs[t] - logf(se[t] + rest);
    }
    float tot = blk_reduce1(lp, wred1, t);
    return -tot;
}

// ---------------------------------------------------------------------------
// Kernel 2 (R10 champion, restored verbatim): one block per batch. Merge LSE
// partials, DIRECT per-segment sums of p2 (4 threads/segment), 2x ListMLE,
// parallel span loss; atomicAdd into out.
// ---------------------------------------------------------------------------
__global__ __launch_bounds__(256) void batch_kernel(
    const float*  __restrict__ scores,
    const float4* __restrict__ lse_part,
    const int*    __restrict__ tt,
    const int*    __restrict__ sent_starts,
    const int*    __restrict__ para_starts,
    const float*  __restrict__ para_labels,
    const float*  __restrict__ sp_labels,
    const int*    __restrict__ starts,
    const int*    __restrict__ ends,
    float* __restrict__ out)
{
    const int b = blockIdx.x;
    const int t = threadIdx.x;
    const int lane = t & 63, w = t >> 6;

    __shared__ float4 lsew[4];
    __shared__ float  wred1[4];
    __shared__ float  fsb[1 + NSEG], flb[1 + NSEG], seb[1 + NSEG];
    __shared__ float  lse_sh[2];
    __shared__ int    ssh[NSEG + 1];

    const float* p0 = scores + 0 * BS + b * S;
    const float* p1 = scores + 1 * BS + b * S;
    const float* p2 = scores + 2 * BS + b * S;
    const float* p3 = scores + 3 * BS + b * S;
    const int*   ttb = tt + b * S;

    if (t < NSEG + 1) ssh[t] = sent_starts[b * (NSEG + 1) + t];

    // ---- merge 256 LSE partials ---------------------------------------------
    {
        float4 P = lse_part[b * BLKS_PER_B + t];
        float2 L0 = make_float2(P.x, P.y);
        float2 L1 = make_float2(P.z, P.w);
#pragma unroll
        for (int off = 32; off > 0; off >>= 1) {
            float2 O0 = make_float2(__shfl_xor(L0.x, off), __shfl_xor(L0.y, off));
            float2 O1 = make_float2(__shfl_xor(L1.x, off), __shfl_xor(L1.y, off));
            L0 = lse_merge(L0, O0);
            L1 = lse_merge(L1, O1);
        }
        if (lane == 0) lsew[w] = make_float4(L0.x, L0.y, L1.x, L1.y);
        __syncthreads();
        if (t == 0) {
            float2 M0 = make_float2(lsew[0].x, lsew[0].y);
            float2 M1 = make_float2(lsew[0].z, lsew[0].w);
#pragma unroll
            for (int i = 1; i < 4; ++i) {
                M0 = lse_merge(M0, make_float2(lsew[i].x, lsew[i].y));
                M1 = lse_merge(M1, make_float2(lsew[i].z, lsew[i].w));
            }
            lse_sh[0] = M0.x + logf(M0.y);
            lse_sh[1] = M1.x + logf(M1.y);
        }
    }

    // ---- direct per-segment sums of p2 (4 threads per segment) --------------
    {
        const int j  = t >> 2;        // segment 0..63
        const int l4 = t & 3;
        int st = ssh[j];
        int en = ssh[j + 1];
        if (en != -1) {
            int stc = min(max(st, 0), S);
            int enc = max(min(max(en, 0), S), stc + 1);
            float x = 0.f;
            for (int s = stc + l4; s < enc; s += 4) x += p2[s];
            x += __shfl_xor(x, 1);
            x += __shfl_xor(x, 2);
            if (l4 == 0) {
                fsb[1 + j] = x / (float)(enc - stc);
                flb[1 + j] = sp_labels[b * NSEG + j];
            }
        } else {
            if (l4 == 0) {
                fsb[1 + j] = p2[S - 1];       // d_sp at last row
                flb[1 + j] = sp_labels[b * NSEG + j];
            }
        }
        if (t == 0) { fsb[0] = p2[0]; flb[0] = 0.5f; }   // sent_thres
    }
    __syncthreads();
    float sp_loss_b = listmle_block(fsb, flb, seb, 1 + NSEG, wred1, t);

    // ---- rank ListMLE -------------------------------------------------------
    if (t == 0) { fsb[0] = p3[0]; flb[0] = 0.5f; }
    if (t < NPARA) {
        int ps = para_starts[b * NPARA + t];
        fsb[1 + t] = p3[ps];
        flb[1 + t] = para_labels[b * NPARA + t];
    }
    __syncthreads();
    float rank_loss_b = listmle_block(fsb, flb, seb, 1 + NPARA, wred1, t);

    // ---- span loss (parallel over answers) ----------------------------------
    float e_a = 0.f;
    if (t < NA) {
        const float lse0 = lse_sh[0], lse1 = lse_sh[1];
        int tsv = starts[b * NA + t];
        int tev = ends[b * NA + t];
        float lt = 0.f;
        if (tsv != -1) {
            int sf = min(max(tsv, 0), S - 1);
            float sl = (ttb[sf] == 1) ? p0[sf] : -INFINITY;
            lt += -(sl - lse0);
        }
        if (tev != -1) {
            int sf = min(max(tev, 0), S - 1);
            float el = (ttb[sf] == 1) ? p1[sf] : -INFINITY;
            lt += -(el - lse1);
        }
        float lp = -lt;
        e_a = (lp == 0.0f) ? 0.f : expf(lp);
    }
#pragma unroll
    for (int off = 4; off > 0; off >>= 1) e_a += __shfl_xor(e_a, off, 8);
    if (t == 0) {
        float logm = (e_a > 0.f) ? logf(e_a) : 0.f;
        atomicAdd(out + 0, rank_loss_b + sp_loss_b - logm);
        atomicAdd(out + 1, rank_loss_b);
        atomicAdd(out + 2, sp_loss_b);
    }
}

extern "C" void kernel_launch(void* const* d_in, const int* in_sizes, int n_in,
                              void* d_out, int out_size, void* d_ws, size_t ws_size,
                              hipStream_t stream)
{
    const float* seq         = (const float*)d_in[0];
    const int*   tt          = (const int*)  d_in[1];
    const int*   sent_starts = (const int*)  d_in[2];
    const int*   para_starts = (const int*)  d_in[3];
    const float* para_labels = (const float*)d_in[4];
    const float* sp_labels   = (const float*)d_in[5];
    const int*   starts      = (const int*)  d_in[6];
    const int*   ends        = (const int*)  d_in[7];
    const float* Wqa         = (const float*)d_in[8];
    const float* Wrank       = (const float*)d_in[10];
    const float* Wsp         = (const float*)d_in[12];

    float*  out      = (float*)d_out;
    float*  scores   = (float*)d_ws;                       // planar (4, B*S)
    float4* lse_part = (float4*)(scores + 4 * (size_t)BS); // NBLK float4

    dots_kernel<<<NBLK, 256, 0, stream>>>(seq, Wqa, Wsp, Wrank, tt,
                                          scores, lse_part, out);
    batch_kernel<<<B, 256, 0, stream>>>(scores, lse_part, tt, sent_starts,
                                        para_starts, para_labels, sp_labels,
                                        starts, ends, out);
}